// Round 10
// baseline (1662.473 us; speedup 1.0000x reference)
//
#include <hip/hip_runtime.h>

// Bijective XCD-aware block swizzle (m204 variant; safe for nwg % 8 != 0).
__device__ __forceinline__ int xcd_swizzle(int bid, int nwg) {
    int q = nwg >> 3, r = nwg & 7;
    int xcd = bid & 7, idx = bid >> 3;
    return (xcd < r) ? xcd * (q + 1) + idx
                     : r * (q + 1) + (xcd - r) * q + idx;
}

// ---------------------------------------------------------------------------
// Stage 1 v2: conv1 (11x11, Cin=1, Cout=32) + ReLU + maxpool 3x3 s2 ceil.
// ---------------------------------------------------------------------------
__global__ __launch_bounds__(256, 4) void conv1_pool_v2_kernel(
    const float* __restrict__ x, const float* __restrict__ w,
    const float* __restrict__ bias, float* __restrict__ out)
{
    const int tile = blockIdx.x;          // 0..24
    const int cog  = blockIdx.y;          // 0..3  (8 couts each)
    const int b    = blockIdx.z;          // 0..31
    const int ty = tile / 5, tx = tile % 5;
    const int pr0 = ty * 16, pc0 = tx * 16;   // pooled origin
    const int cr0 = pr0 * 2, cc0 = pc0 * 2;   // conv origin

    __shared__ float in_s[43 * 44];
    __shared__ float w_s[8][121];
    __shared__ float hp_s[33][8][17];

    const int tid = threadIdx.x;

    const float* xb = x + b * 152 * 152;
    for (int i = tid; i < 43 * 44; i += 256) {
        int r = i / 44, c = i - r * 44;
        int ir = cr0 + r, ic = cc0 + c;
        in_s[i] = (ir < 152 && ic < 152) ? xb[ir * 152 + ic] : 0.f;
    }
    for (int i = tid; i < 8 * 121; i += 256) {
        int co = i / 121, k = i - co * 121;
        w_s[co][k] = w[(cog * 8 + co) * 121 + k];
    }
    __syncthreads();

    for (int task = tid; task < 264; task += 256) {
        const int co  = task & 7;
        const int row = task >> 3;
        float hmax[16];
        if (cr0 + row < 142) {
            float acc[33];
            #pragma unroll
            for (int px = 0; px < 33; ++px) acc[px] = 0.f;
            #pragma unroll 1
            for (int kh = 0; kh < 11; ++kh) {
                float4 rq[11];
                #pragma unroll
                for (int j = 0; j < 11; ++j)
                    rq[j] = *reinterpret_cast<const float4*>(
                        &in_s[(row + kh) * 44 + j * 4]);
                const float* rr = reinterpret_cast<const float*>(rq);
                #pragma unroll
                for (int kw = 0; kw < 11; ++kw) {
                    float wv = w_s[co][kh * 11 + kw];
                    #pragma unroll
                    for (int px = 0; px < 33; ++px)
                        acc[px] += rr[px + kw] * wv;
                }
            }
            const float bv = bias[cog * 8 + co];
            #pragma unroll
            for (int px = 0; px < 33; ++px) {
                float v = fmaxf(acc[px] + bv, 0.f);
                acc[px] = (cc0 + px < 142) ? v : 0.f;
            }
            #pragma unroll
            for (int pc = 0; pc < 16; ++pc)
                hmax[pc] = fmaxf(fmaxf(acc[2 * pc], acc[2 * pc + 1]), acc[2 * pc + 2]);
        } else {
            #pragma unroll
            for (int pc = 0; pc < 16; ++pc) hmax[pc] = 0.f;
        }
        #pragma unroll
        for (int pc = 0; pc < 16; ++pc) hp_s[row][co][pc] = hmax[pc];
    }
    __syncthreads();

    for (int t = tid; t < 2048; t += 256) {
        int co = t >> 8, r = t & 255;
        int ppy = r >> 4, ppc = r & 15;
        float v = fmaxf(fmaxf(hp_s[2 * ppy][co][ppc], hp_s[2 * ppy + 1][co][ppc]),
                        hp_s[2 * ppy + 2][co][ppc]);
        int pr = pr0 + ppy, pc = pc0 + ppc;
        if (pr < 71 && pc < 71)
            out[((b * 32 + cog * 8 + co) * 71 + pr) * 71 + pc] = v;
    }
}

// ---------------------------------------------------------------------------
// Stage 2: conv2 (9x9, Cin=32, Cout=16) + ReLU   (unchanged)
// ---------------------------------------------------------------------------
__global__ __launch_bounds__(256) void conv2_kernel(
    const float* __restrict__ in, const float* __restrict__ w,
    const float* __restrict__ bias, float* __restrict__ out)
{
    const int tile = blockIdx.x;
    const int b = blockIdx.y;
    const int ty = tile / 4, tx = tile % 4;
    const int oh0 = ty * 16, ow0 = tx * 16;

    __shared__ float in_s[4][24][25];
    __shared__ float w_s[16][324];

    const int tid = threadIdx.x;
    const int co = tid / 16;
    const int py = tid % 16;

    float acc[16];
    #pragma unroll
    for (int i = 0; i < 16; ++i) acc[i] = 0.f;

    for (int cc = 0; cc < 8; ++cc) {
        for (int i = tid; i < 4 * 24 * 24; i += 256) {
            int ci = i / 576, r = (i / 24) % 24, c = i % 24;
            int ih = oh0 + r, iw = ow0 + c;
            float v = 0.f;
            if (ih < 71 && iw < 71)
                v = in[((b * 32 + cc * 4 + ci) * 71 + ih) * 71 + iw];
            in_s[ci][r][c] = v;
        }
        for (int i = tid; i < 16 * 324; i += 256) {
            int c2 = i / 324, t = i % 324;
            w_s[c2][t] = w[c2 * 2592 + cc * 324 + t];
        }
        __syncthreads();

        #pragma unroll 1
        for (int ci = 0; ci < 4; ++ci) {
            #pragma unroll 1
            for (int kh = 0; kh < 9; ++kh) {
                float rr[24];
                #pragma unroll
                for (int c = 0; c < 24; ++c) rr[c] = in_s[ci][py + kh][c];
                #pragma unroll
                for (int kw = 0; kw < 9; ++kw) {
                    float wv = w_s[co][ci * 81 + kh * 9 + kw];
                    #pragma unroll
                    for (int px = 0; px < 16; ++px)
                        acc[px] += rr[kw + px] * wv;
                }
            }
        }
        __syncthreads();
    }

    const int oh = oh0 + py;
    if (oh < 63) {
        const float bv = bias[co];
        #pragma unroll
        for (int px = 0; px < 16; ++px) {
            int ow = ow0 + px;
            if (ow < 63)
                out[((b * 16 + co) * 63 + oh) * 63 + ow] = fmaxf(acc[px] + bv, 0.f);
        }
    }
}

// ---------------------------------------------------------------------------
// Stages 3-5 v8: locally-connected conv + ReLU.
// = v6's cooperative LDS double-buffer staging, BUT the per-pass barrier is
// raw s_barrier + lgkmcnt(0) only (no vmcnt drain) -> weight/gather
// prefetch loads stay in flight across the barrier; compiler emits counted
// vmcnt for their register uses. Offset table in LDS, read as one int4
// b128/pass (kills magic-div VALU). unroll 2 -> wv=wvn copy-propagates
// (no vmcnt(0)-forcing reg move). XCD-swizzled pos (write-amp fix, r9).
// 512 thr = bg(4) x cog(4) x kl(32); acc[8][4]=32 regs; LDS 32+<=5.6 KB.
// ---------------------------------------------------------------------------
template<int KS, int STRIDE, int HIN, int WIN, int HOUT, int WOUT>
__global__ __launch_bounds__(512) void lc_v8_kernel(
    const float* __restrict__ in, const float* __restrict__ w,
    const float* __restrict__ bias, float* __restrict__ out)
{
    constexpr int K     = 16 * KS * KS;
    constexpr int K2    = KS * KS;
    constexpr int NPASS = (K + 127) / 128;
    constexpr int KPAD  = NPASS * 128;
    constexpr int HW    = HOUT * WOUT;
    constexpr int CHW   = 16 * HIN * WIN;

    __shared__ float patch_s[2][4096];     // 32 KB
    __shared__ int   base_s[KPAD];         // <= 5.6 KB

    const int tid = threadIdx.x;
    const int pos = xcd_swizzle(blockIdx.x, HW);
    const int oh = pos / WOUT, ow = pos % WOUT;
    const int posoff = (oh * STRIDE) * WIN + ow * STRIDE;

    // position-independent gather-offset table (built once)
    for (int k = tid; k < KPAD; k += 512) {
        int v = 0;
        if (k < K) {
            int ci = k / K2;
            int r  = k - ci * K2;
            int kh = r / KS, kw = r - kh * KS;
            v = ci * (HIN * WIN) + kh * WIN + kw;
        }
        base_s[k] = v;
    }

    const int kl  = tid & 31;
    const int cog = (tid >> 5) & 3;
    const int bg  = tid >> 7;              // 0..3
    const int b0  = bg * 8;

    // staging role: thread stages float4 #tid (batch sb) and #tid+512 (sb+16)
    const int sb = tid >> 5;               // 0..15
    const int k0 = (tid & 31) * 4;         // k offset within 128-window
    const float* gsrc0 = in + sb * CHW + posoff;
    const float* gsrc1 = gsrc0 + 16 * CHW;

    const float* wbase = w + (size_t)pos * 16 * K;

    float acc[8][4];
    #pragma unroll
    for (int i = 0; i < 8; ++i)
        #pragma unroll
        for (int j = 0; j < 4; ++j) acc[i][j] = 0.f;

    float4 wv[4], wvn[4];

    __syncthreads();                       // table ready (full sync, once)

    {   // prologue: pass-0 weights + patch
        const int kw4 = kl * 4;
        #pragma unroll
        for (int cj = 0; cj < 4; ++cj)
            wv[cj] = (kw4 < K)
                ? *reinterpret_cast<const float4*>(wbase + (size_t)(cog * 4 + cj) * K + kw4)
                : make_float4(0.f, 0.f, 0.f, 0.f);
        int4 off4 = *reinterpret_cast<const int4*>(&base_s[k0]);
        float t0x = gsrc0[off4.x], t0y = gsrc0[off4.y],
              t0z = gsrc0[off4.z], t0w = gsrc0[off4.w];
        float t1x = gsrc1[off4.x], t1y = gsrc1[off4.y],
              t1z = gsrc1[off4.z], t1w = gsrc1[off4.w];
        *reinterpret_cast<float4*>(&patch_s[0][tid * 4]) =
            make_float4(t0x, t0y, t0z, t0w);
        *reinterpret_cast<float4*>(&patch_s[0][2048 + tid * 4]) =
            make_float4(t1x, t1y, t1z, t1w);
    }
    asm volatile("s_waitcnt lgkmcnt(0)" ::: "memory");
    __builtin_amdgcn_s_barrier();

    int cur = 0;
    #pragma unroll 2
    for (int ps = 0; ps < NPASS; ++ps) {
        const bool more = (ps + 1 < NPASS);
        float t0x, t0y, t0z, t0w, t1x, t1y, t1z, t1w;
        if (more) {
            int4 off4 = *reinterpret_cast<const int4*>(&base_s[(ps + 1) * 128 + k0]);
            t0x = gsrc0[off4.x]; t0y = gsrc0[off4.y];
            t0z = gsrc0[off4.z]; t0w = gsrc0[off4.w];
            t1x = gsrc1[off4.x]; t1y = gsrc1[off4.y];
            t1z = gsrc1[off4.z]; t1w = gsrc1[off4.w];
            const int kw4n = (ps + 1) * 128 + kl * 4;
            #pragma unroll
            for (int cj = 0; cj < 4; ++cj)
                wvn[cj] = (kw4n < K)
                    ? *reinterpret_cast<const float4*>(wbase + (size_t)(cog * 4 + cj) * K + kw4n)
                    : make_float4(0.f, 0.f, 0.f, 0.f);
        }
        // compute current pass: 8 x (ds_read_b128 + 16 FMA)
        #pragma unroll
        for (int bi = 0; bi < 8; ++bi) {
            float4 pv = *reinterpret_cast<const float4*>(
                &patch_s[cur][(b0 + bi) * 128 + kl * 4]);
            #pragma unroll
            for (int cj = 0; cj < 4; ++cj)
                acc[bi][cj] += pv.x * wv[cj].x + pv.y * wv[cj].y
                             + pv.z * wv[cj].z + pv.w * wv[cj].w;
        }
        if (more) {
            *reinterpret_cast<float4*>(&patch_s[cur ^ 1][tid * 4]) =
                make_float4(t0x, t0y, t0z, t0w);
            *reinterpret_cast<float4*>(&patch_s[cur ^ 1][2048 + tid * 4]) =
                make_float4(t1x, t1y, t1z, t1w);
            #pragma unroll
            for (int cj = 0; cj < 4; ++cj) wv[cj] = wvn[cj];
        }
        // LDS-only barrier: ds reads+writes retired (lgkmcnt), global
        // prefetch loads stay outstanding (counted vmcnt at their uses).
        asm volatile("s_waitcnt lgkmcnt(0)" ::: "memory");
        __builtin_amdgcn_s_barrier();
        cur ^= 1;
    }

    // reduce over the 32 kl lanes (masks 1..16 stay within 32-lane halves)
    #pragma unroll
    for (int bi = 0; bi < 8; ++bi)
        #pragma unroll
        for (int cj = 0; cj < 4; ++cj) {
            float v = acc[bi][cj];
            v += __shfl_xor(v, 1);
            v += __shfl_xor(v, 2);
            v += __shfl_xor(v, 4);
            v += __shfl_xor(v, 8);
            v += __shfl_xor(v, 16);
            acc[bi][cj] = v;
        }

    if (kl == 0) {
        float bv[4];
        #pragma unroll
        for (int cj = 0; cj < 4; ++cj)
            bv[cj] = bias[(cog * 4 + cj) * HW + pos];
        #pragma unroll
        for (int bi = 0; bi < 8; ++bi)
            #pragma unroll
            for (int cj = 0; cj < 4; ++cj) {
                int b = b0 + bi, co = cog * 4 + cj;
                out[(b * 16 + co) * HW + pos] = fmaxf(acc[bi][cj] + bv[cj], 0.f);
            }
    }
}

// ---------------------------------------------------------------------------
// Stage 6 v6: FC (32,7056)@(4096,7056)^T — barrier-free template (contiguous
// float4 patch loads; no gather disease). Grid (256,4); partials -> reduce.
// ---------------------------------------------------------------------------
__global__ __launch_bounds__(512) void fc_v6_kernel(
    const float* __restrict__ in, const float* __restrict__ w,
    float* __restrict__ part)
{
    constexpr int K = 7056, KR = 1764;
    constexpr int NPASS = (KR + 127) / 128;   // 14

    const int tid  = threadIdx.x;
    const int oblk = blockIdx.x;              // 0..255
    const int ks   = blockIdx.y;              // 0..3
    const int kbeg = ks * KR, klim = kbeg + KR;

    const int kl  = tid & 31;
    const int cog = (tid >> 5) & 3;
    const int bg  = tid >> 7;
    const int b0  = bg * 8;

    const float* pbase = in + b0 * K;
    const float* wbase = w + (size_t)(oblk * 16) * K;
    const float4 z4 = make_float4(0.f, 0.f, 0.f, 0.f);

    float acc[8][4];
    #pragma unroll
    for (int i = 0; i < 8; ++i)
        #pragma unroll
        for (int j = 0; j < 4; ++j) acc[i][j] = 0.f;

    float4 wv[4], wvn[4];
    {
        const int kw4 = kbeg + kl * 4;
        #pragma unroll
        for (int cj = 0; cj < 4; ++cj)
            wv[cj] = (kw4 < klim)
                ? *reinterpret_cast<const float4*>(wbase + (size_t)(cog * 4 + cj) * K + kw4)
                : z4;
    }

    #pragma unroll 2
    for (int ps = 0; ps < NPASS; ++ps) {
        const int kb = kbeg + ps * 128 + kl * 4;
        const bool more = (ps + 1 < NPASS);
        if (more) {
            const int kw4n = kbeg + (ps + 1) * 128 + kl * 4;
            #pragma unroll
            for (int cj = 0; cj < 4; ++cj)
                wvn[cj] = (kw4n < klim)
                    ? *reinterpret_cast<const float4*>(wbase + (size_t)(cog * 4 + cj) * K + kw4n)
                    : z4;
        }
        #pragma unroll
        for (int bi = 0; bi < 8; ++bi) {
            float4 pv = (kb < klim)
                ? *reinterpret_cast<const float4*>(pbase + bi * K + kb)
                : z4;
            #pragma unroll
            for (int cj = 0; cj < 4; ++cj)
                acc[bi][cj] += pv.x * wv[cj].x + pv.y * wv[cj].y
                             + pv.z * wv[cj].z + pv.w * wv[cj].w;
        }
        if (more) {
            #pragma unroll
            for (int cj = 0; cj < 4; ++cj) wv[cj] = wvn[cj];
        }
    }

    #pragma unroll
    for (int bi = 0; bi < 8; ++bi)
        #pragma unroll
        for (int cj = 0; cj < 4; ++cj) {
            float v = acc[bi][cj];
            v += __shfl_xor(v, 1);
            v += __shfl_xor(v, 2);
            v += __shfl_xor(v, 4);
            v += __shfl_xor(v, 8);
            v += __shfl_xor(v, 16);
            acc[bi][cj] = v;
        }

    if (kl == 0) {
        #pragma unroll
        for (int bi = 0; bi < 8; ++bi)
            #pragma unroll
            for (int cj = 0; cj < 4; ++cj)
                part[(size_t)(ks * 32 + b0 + bi) * 4096 + oblk * 16 + cog * 4 + cj] =
                    acc[bi][cj];
    }
}

__global__ __launch_bounds__(256) void fc_reduce_kernel(
    const float* __restrict__ part, const float* __restrict__ bias,
    float* __restrict__ out)
{
    int i4 = blockIdx.x * 256 + threadIdx.x;
    if (i4 >= 32768) return;
    int b = i4 >> 10, o4 = i4 & 1023;
    const size_t stride = (size_t)32 * 4096;
    const float* base = part + (size_t)b * 4096 + o4 * 4;
    float4 s0 = *reinterpret_cast<const float4*>(base);
    float4 s1 = *reinterpret_cast<const float4*>(base + stride);
    float4 s2 = *reinterpret_cast<const float4*>(base + 2 * stride);
    float4 s3 = *reinterpret_cast<const float4*>(base + 3 * stride);
    float4 bv = *reinterpret_cast<const float4*>(bias + o4 * 4);
    float4 r;
    r.x = s0.x + s1.x + s2.x + s3.x + bv.x;
    r.y = s0.y + s1.y + s2.y + s3.y + bv.y;
    r.z = s0.z + s1.z + s2.z + s3.z + bv.z;
    r.w = s0.w + s1.w + s2.w + s3.w + bv.w;
    *reinterpret_cast<float4*>(out + b * 4096 + o4 * 4) = r;
}

// ---------------------------------------------------------------------------
extern "C" void kernel_launch(void* const* d_in, const int* in_sizes, int n_in,
                              void* d_out, int out_size, void* d_ws, size_t ws_size,
                              hipStream_t stream) {
    const float* x    = (const float*)d_in[0];
    const float* c1w  = (const float*)d_in[1];
    const float* c1b  = (const float*)d_in[2];
    const float* c2w  = (const float*)d_in[3];
    const float* c2b  = (const float*)d_in[4];
    const float* lc1w = (const float*)d_in[5];
    const float* lc1b = (const float*)d_in[6];
    const float* lc2w = (const float*)d_in[7];
    const float* lc2b = (const float*)d_in[8];
    const float* lc3w = (const float*)d_in[9];
    const float* lc3b = (const float*)d_in[10];
    const float* fcw  = (const float*)d_in[11];
    const float* fcb  = (const float*)d_in[12];
    float* out = (float*)d_out;

    float* ws  = (float*)d_ws;
    float* h1p = ws;                 // 32*32*71*71 = 5,161,472
    float* h2  = h1p + 5161472;      // 32*16*63*63 = 2,032,128
    float* h3  = h2  + 2032128;      // 32*16*55*55 = 1,548,800
    float* h4  = h3  + 1548800;      // 32*16*25*25 =   320,000
    float* h5  = h4  + 320000;       // 32*16*21*21 =   225,792
    float* fc_part = h1p;            // conv1 output dead by fc time

    conv1_pool_v2_kernel<<<dim3(25, 4, 32), 256, 0, stream>>>(x, c1w, c1b, h1p);
    conv2_kernel<<<dim3(16, 32), 256, 0, stream>>>(h1p, c2w, c2b, h2);
    lc_v8_kernel<9, 1, 63, 63, 55, 55><<<dim3(55 * 55), 512, 0, stream>>>(h2, lc1w, lc1b, h3);
    lc_v8_kernel<7, 2, 55, 55, 25, 25><<<dim3(25 * 25), 512, 0, stream>>>(h3, lc2w, lc2b, h4);
    lc_v8_kernel<5, 1, 25, 25, 21, 21><<<dim3(21 * 21), 512, 0, stream>>>(h4, lc3w, lc3b, h5);
    fc_v6_kernel<<<dim3(256, 4), 512, 0, stream>>>(h5, fcw, fc_part);
    fc_reduce_kernel<<<dim3(128), 256, 0, stream>>>(fc_part, fcb, out);
}

// Round 11
// 883.991 us; speedup vs baseline: 1.8806x; 1.8806x over previous
//
#include <hip/hip_runtime.h>

// Bijective XCD-aware block swizzle (m204 variant; safe for nwg % 8 != 0).
__device__ __forceinline__ int xcd_swizzle(int bid, int nwg) {
    int q = nwg >> 3, r = nwg & 7;
    int xcd = bid & 7, idx = bid >> 3;
    return (xcd < r) ? xcd * (q + 1) + idx
                     : r * (q + 1) + (xcd - r) * q + idx;
}

// ---------------------------------------------------------------------------
// Stage 1 v2: conv1 (11x11, Cin=1, Cout=32) + ReLU + maxpool 3x3 s2 ceil.
// ---------------------------------------------------------------------------
__global__ __launch_bounds__(256, 4) void conv1_pool_v2_kernel(
    const float* __restrict__ x, const float* __restrict__ w,
    const float* __restrict__ bias, float* __restrict__ out)
{
    const int tile = blockIdx.x;          // 0..24
    const int cog  = blockIdx.y;          // 0..3  (8 couts each)
    const int b    = blockIdx.z;          // 0..31
    const int ty = tile / 5, tx = tile % 5;
    const int pr0 = ty * 16, pc0 = tx * 16;   // pooled origin
    const int cr0 = pr0 * 2, cc0 = pc0 * 2;   // conv origin

    __shared__ float in_s[43 * 44];
    __shared__ float w_s[8][121];
    __shared__ float hp_s[33][8][17];

    const int tid = threadIdx.x;

    const float* xb = x + b * 152 * 152;
    for (int i = tid; i < 43 * 44; i += 256) {
        int r = i / 44, c = i - r * 44;
        int ir = cr0 + r, ic = cc0 + c;
        in_s[i] = (ir < 152 && ic < 152) ? xb[ir * 152 + ic] : 0.f;
    }
    for (int i = tid; i < 8 * 121; i += 256) {
        int co = i / 121, k = i - co * 121;
        w_s[co][k] = w[(cog * 8 + co) * 121 + k];
    }
    __syncthreads();

    for (int task = tid; task < 264; task += 256) {
        const int co  = task & 7;
        const int row = task >> 3;
        float hmax[16];
        if (cr0 + row < 142) {
            float acc[33];
            #pragma unroll
            for (int px = 0; px < 33; ++px) acc[px] = 0.f;
            #pragma unroll 1
            for (int kh = 0; kh < 11; ++kh) {
                float4 rq[11];
                #pragma unroll
                for (int j = 0; j < 11; ++j)
                    rq[j] = *reinterpret_cast<const float4*>(
                        &in_s[(row + kh) * 44 + j * 4]);
                const float* rr = reinterpret_cast<const float*>(rq);
                #pragma unroll
                for (int kw = 0; kw < 11; ++kw) {
                    float wv = w_s[co][kh * 11 + kw];
                    #pragma unroll
                    for (int px = 0; px < 33; ++px)
                        acc[px] += rr[px + kw] * wv;
                }
            }
            const float bv = bias[cog * 8 + co];
            #pragma unroll
            for (int px = 0; px < 33; ++px) {
                float v = fmaxf(acc[px] + bv, 0.f);
                acc[px] = (cc0 + px < 142) ? v : 0.f;
            }
            #pragma unroll
            for (int pc = 0; pc < 16; ++pc)
                hmax[pc] = fmaxf(fmaxf(acc[2 * pc], acc[2 * pc + 1]), acc[2 * pc + 2]);
        } else {
            #pragma unroll
            for (int pc = 0; pc < 16; ++pc) hmax[pc] = 0.f;
        }
        #pragma unroll
        for (int pc = 0; pc < 16; ++pc) hp_s[row][co][pc] = hmax[pc];
    }
    __syncthreads();

    for (int t = tid; t < 2048; t += 256) {
        int co = t >> 8, r = t & 255;
        int ppy = r >> 4, ppc = r & 15;
        float v = fmaxf(fmaxf(hp_s[2 * ppy][co][ppc], hp_s[2 * ppy + 1][co][ppc]),
                        hp_s[2 * ppy + 2][co][ppc]);
        int pr = pr0 + ppy, pc = pc0 + ppc;
        if (pr < 71 && pc < 71)
            out[((b * 32 + cog * 8 + co) * 71 + pr) * 71 + pc] = v;
    }
}

// ---------------------------------------------------------------------------
// Stage 2: conv2 (9x9, Cin=32, Cout=16) + ReLU   (unchanged)
// ---------------------------------------------------------------------------
__global__ __launch_bounds__(256) void conv2_kernel(
    const float* __restrict__ in, const float* __restrict__ w,
    const float* __restrict__ bias, float* __restrict__ out)
{
    const int tile = blockIdx.x;
    const int b = blockIdx.y;
    const int ty = tile / 4, tx = tile % 4;
    const int oh0 = ty * 16, ow0 = tx * 16;

    __shared__ float in_s[4][24][25];
    __shared__ float w_s[16][324];

    const int tid = threadIdx.x;
    const int co = tid / 16;
    const int py = tid % 16;

    float acc[16];
    #pragma unroll
    for (int i = 0; i < 16; ++i) acc[i] = 0.f;

    for (int cc = 0; cc < 8; ++cc) {
        for (int i = tid; i < 4 * 24 * 24; i += 256) {
            int ci = i / 576, r = (i / 24) % 24, c = i % 24;
            int ih = oh0 + r, iw = ow0 + c;
            float v = 0.f;
            if (ih < 71 && iw < 71)
                v = in[((b * 32 + cc * 4 + ci) * 71 + ih) * 71 + iw];
            in_s[ci][r][c] = v;
        }
        for (int i = tid; i < 16 * 324; i += 256) {
            int c2 = i / 324, t = i % 324;
            w_s[c2][t] = w[c2 * 2592 + cc * 324 + t];
        }
        __syncthreads();

        #pragma unroll 1
        for (int ci = 0; ci < 4; ++ci) {
            #pragma unroll 1
            for (int kh = 0; kh < 9; ++kh) {
                float rr[24];
                #pragma unroll
                for (int c = 0; c < 24; ++c) rr[c] = in_s[ci][py + kh][c];
                #pragma unroll
                for (int kw = 0; kw < 9; ++kw) {
                    float wv = w_s[co][ci * 81 + kh * 9 + kw];
                    #pragma unroll
                    for (int px = 0; px < 16; ++px)
                        acc[px] += rr[kw + px] * wv;
                }
            }
        }
        __syncthreads();
    }

    const int oh = oh0 + py;
    if (oh < 63) {
        const float bv = bias[co];
        #pragma unroll
        for (int px = 0; px < 16; ++px) {
            int ow = ow0 + px;
            if (ow < 63)
                out[((b * 16 + co) * 63 + oh) * 63 + ow] = fmaxf(acc[px] + bv, 0.f);
        }
    }
}

// ---------------------------------------------------------------------------
// Stages 3-5 v9: locally-connected conv + ReLU.
// = v8 (LDS dbuf staging + raw lgkmcnt-only barrier + int4 offset table +
// XCD swizzle) but with #pragma unroll 1 on the pass loop. v8's unroll-2
// doubled live pipeline state -> 128 VGPR + 1.7 GB scratch. With unroll 1,
// demand ~= v6's 84 regs; the raw barrier (no vmcnt drain) lets the weight
// prefetch survive across passes -> counted vmcnt at use, stalls hidden.
// 512 thr = bg(4) x cog(4) x kl(32); acc[8][4]=32 regs.
// ---------------------------------------------------------------------------
template<int KS, int STRIDE, int HIN, int WIN, int HOUT, int WOUT>
__global__ __launch_bounds__(512) void lc_v9_kernel(
    const float* __restrict__ in, const float* __restrict__ w,
    const float* __restrict__ bias, float* __restrict__ out)
{
    constexpr int K     = 16 * KS * KS;
    constexpr int K2    = KS * KS;
    constexpr int NPASS = (K + 127) / 128;
    constexpr int KPAD  = NPASS * 128;
    constexpr int HW    = HOUT * WOUT;
    constexpr int CHW   = 16 * HIN * WIN;

    __shared__ float patch_s[2][4096];     // 32 KB
    __shared__ int   base_s[KPAD];         // <= 5.6 KB

    const int tid = threadIdx.x;
    const int pos = xcd_swizzle(blockIdx.x, HW);
    const int oh = pos / WOUT, ow = pos % WOUT;
    const int posoff = (oh * STRIDE) * WIN + ow * STRIDE;

    // position-independent gather-offset table (built once)
    for (int k = tid; k < KPAD; k += 512) {
        int v = 0;
        if (k < K) {
            int ci = k / K2;
            int r  = k - ci * K2;
            int kh = r / KS, kw = r - kh * KS;
            v = ci * (HIN * WIN) + kh * WIN + kw;
        }
        base_s[k] = v;
    }

    const int kl  = tid & 31;
    const int cog = (tid >> 5) & 3;
    const int bg  = tid >> 7;              // 0..3
    const int b0  = bg * 8;

    // staging role: thread stages float4 #tid (batch sb) and #tid+512 (sb+16)
    const int sb = tid >> 5;               // 0..15
    const int k0 = (tid & 31) * 4;         // k offset within 128-window
    const float* gsrc0 = in + sb * CHW + posoff;
    const float* gsrc1 = gsrc0 + 16 * CHW;

    const float* wbase = w + (size_t)pos * 16 * K;

    float acc[8][4];
    #pragma unroll
    for (int i = 0; i < 8; ++i)
        #pragma unroll
        for (int j = 0; j < 4; ++j) acc[i][j] = 0.f;

    float4 wv[4], wvn[4];

    __syncthreads();                       // table ready (full sync, once)

    {   // prologue: pass-0 weights + patch
        const int kw4 = kl * 4;
        #pragma unroll
        for (int cj = 0; cj < 4; ++cj)
            wv[cj] = (kw4 < K)
                ? *reinterpret_cast<const float4*>(wbase + (size_t)(cog * 4 + cj) * K + kw4)
                : make_float4(0.f, 0.f, 0.f, 0.f);
        int4 off4 = *reinterpret_cast<const int4*>(&base_s[k0]);
        float t0x = gsrc0[off4.x], t0y = gsrc0[off4.y],
              t0z = gsrc0[off4.z], t0w = gsrc0[off4.w];
        float t1x = gsrc1[off4.x], t1y = gsrc1[off4.y],
              t1z = gsrc1[off4.z], t1w = gsrc1[off4.w];
        *reinterpret_cast<float4*>(&patch_s[0][tid * 4]) =
            make_float4(t0x, t0y, t0z, t0w);
        *reinterpret_cast<float4*>(&patch_s[0][2048 + tid * 4]) =
            make_float4(t1x, t1y, t1z, t1w);
    }
    asm volatile("s_waitcnt lgkmcnt(0)" ::: "memory");
    __builtin_amdgcn_s_barrier();

    int cur = 0;
    #pragma unroll 1
    for (int ps = 0; ps < NPASS; ++ps) {
        const bool more = (ps + 1 < NPASS);
        float t0x, t0y, t0z, t0w, t1x, t1y, t1z, t1w;
        if (more) {
            int4 off4 = *reinterpret_cast<const int4*>(&base_s[(ps + 1) * 128 + k0]);
            t0x = gsrc0[off4.x]; t0y = gsrc0[off4.y];
            t0z = gsrc0[off4.z]; t0w = gsrc0[off4.w];
            t1x = gsrc1[off4.x]; t1y = gsrc1[off4.y];
            t1z = gsrc1[off4.z]; t1w = gsrc1[off4.w];
            const int kw4n = (ps + 1) * 128 + kl * 4;
            #pragma unroll
            for (int cj = 0; cj < 4; ++cj)
                wvn[cj] = (kw4n < K)
                    ? *reinterpret_cast<const float4*>(wbase + (size_t)(cog * 4 + cj) * K + kw4n)
                    : make_float4(0.f, 0.f, 0.f, 0.f);
        }
        // compute current pass: 8 x (ds_read_b128 + 16 FMA)
        #pragma unroll
        for (int bi = 0; bi < 8; ++bi) {
            float4 pv = *reinterpret_cast<const float4*>(
                &patch_s[cur][(b0 + bi) * 128 + kl * 4]);
            #pragma unroll
            for (int cj = 0; cj < 4; ++cj)
                acc[bi][cj] += pv.x * wv[cj].x + pv.y * wv[cj].y
                             + pv.z * wv[cj].z + pv.w * wv[cj].w;
        }
        if (more) {
            *reinterpret_cast<float4*>(&patch_s[cur ^ 1][tid * 4]) =
                make_float4(t0x, t0y, t0z, t0w);
            *reinterpret_cast<float4*>(&patch_s[cur ^ 1][2048 + tid * 4]) =
                make_float4(t1x, t1y, t1z, t1w);
            #pragma unroll
            for (int cj = 0; cj < 4; ++cj) wv[cj] = wvn[cj];
        }
        // LDS-only barrier: ds reads+writes retired (lgkmcnt), global
        // prefetch loads stay outstanding (counted vmcnt at their uses).
        asm volatile("s_waitcnt lgkmcnt(0)" ::: "memory");
        __builtin_amdgcn_s_barrier();
        cur ^= 1;
    }

    // reduce over the 32 kl lanes (masks 1..16 stay within 32-lane halves)
    #pragma unroll
    for (int bi = 0; bi < 8; ++bi)
        #pragma unroll
        for (int cj = 0; cj < 4; ++cj) {
            float v = acc[bi][cj];
            v += __shfl_xor(v, 1);
            v += __shfl_xor(v, 2);
            v += __shfl_xor(v, 4);
            v += __shfl_xor(v, 8);
            v += __shfl_xor(v, 16);
            acc[bi][cj] = v;
        }

    if (kl == 0) {
        float bv[4];
        #pragma unroll
        for (int cj = 0; cj < 4; ++cj)
            bv[cj] = bias[(cog * 4 + cj) * HW + pos];
        #pragma unroll
        for (int bi = 0; bi < 8; ++bi)
            #pragma unroll
            for (int cj = 0; cj < 4; ++cj) {
                int b = b0 + bi, co = cog * 4 + cj;
                out[(b * 16 + co) * HW + pos] = fmaxf(acc[bi][cj] + bv[cj], 0.f);
            }
    }
}

// ---------------------------------------------------------------------------
// Stage 6 v6: FC (32,7056)@(4096,7056)^T — barrier-free template (contiguous
// float4 patch loads; no gather disease). Grid (256,4); partials -> reduce.
// ---------------------------------------------------------------------------
__global__ __launch_bounds__(512) void fc_v6_kernel(
    const float* __restrict__ in, const float* __restrict__ w,
    float* __restrict__ part)
{
    constexpr int K = 7056, KR = 1764;
    constexpr int NPASS = (KR + 127) / 128;   // 14

    const int tid  = threadIdx.x;
    const int oblk = blockIdx.x;              // 0..255
    const int ks   = blockIdx.y;              // 0..3
    const int kbeg = ks * KR, klim = kbeg + KR;

    const int kl  = tid & 31;
    const int cog = (tid >> 5) & 3;
    const int bg  = tid >> 7;
    const int b0  = bg * 8;

    const float* pbase = in + b0 * K;
    const float* wbase = w + (size_t)(oblk * 16) * K;
    const float4 z4 = make_float4(0.f, 0.f, 0.f, 0.f);

    float acc[8][4];
    #pragma unroll
    for (int i = 0; i < 8; ++i)
        #pragma unroll
        for (int j = 0; j < 4; ++j) acc[i][j] = 0.f;

    float4 wv[4], wvn[4];
    {
        const int kw4 = kbeg + kl * 4;
        #pragma unroll
        for (int cj = 0; cj < 4; ++cj)
            wv[cj] = (kw4 < klim)
                ? *reinterpret_cast<const float4*>(wbase + (size_t)(cog * 4 + cj) * K + kw4)
                : z4;
    }

    #pragma unroll 1
    for (int ps = 0; ps < NPASS; ++ps) {
        const int kb = kbeg + ps * 128 + kl * 4;
        const bool more = (ps + 1 < NPASS);
        if (more) {
            const int kw4n = kbeg + (ps + 1) * 128 + kl * 4;
            #pragma unroll
            for (int cj = 0; cj < 4; ++cj)
                wvn[cj] = (kw4n < klim)
                    ? *reinterpret_cast<const float4*>(wbase + (size_t)(cog * 4 + cj) * K + kw4n)
                    : z4;
        }
        #pragma unroll
        for (int bi = 0; bi < 8; ++bi) {
            float4 pv = (kb < klim)
                ? *reinterpret_cast<const float4*>(pbase + bi * K + kb)
                : z4;
            #pragma unroll
            for (int cj = 0; cj < 4; ++cj)
                acc[bi][cj] += pv.x * wv[cj].x + pv.y * wv[cj].y
                             + pv.z * wv[cj].z + pv.w * wv[cj].w;
        }
        if (more) {
            #pragma unroll
            for (int cj = 0; cj < 4; ++cj) wv[cj] = wvn[cj];
        }
    }

    #pragma unroll
    for (int bi = 0; bi < 8; ++bi)
        #pragma unroll
        for (int cj = 0; cj < 4; ++cj) {
            float v = acc[bi][cj];
            v += __shfl_xor(v, 1);
            v += __shfl_xor(v, 2);
            v += __shfl_xor(v, 4);
            v += __shfl_xor(v, 8);
            v += __shfl_xor(v, 16);
            acc[bi][cj] = v;
        }

    if (kl == 0) {
        #pragma unroll
        for (int bi = 0; bi < 8; ++bi)
            #pragma unroll
            for (int cj = 0; cj < 4; ++cj)
                part[(size_t)(ks * 32 + b0 + bi) * 4096 + oblk * 16 + cog * 4 + cj] =
                    acc[bi][cj];
    }
}

__global__ __launch_bounds__(256) void fc_reduce_kernel(
    const float* __restrict__ part, const float* __restrict__ bias,
    float* __restrict__ out)
{
    int i4 = blockIdx.x * 256 + threadIdx.x;
    if (i4 >= 32768) return;
    int b = i4 >> 10, o4 = i4 & 1023;
    const size_t stride = (size_t)32 * 4096;
    const float* base = part + (size_t)b * 4096 + o4 * 4;
    float4 s0 = *reinterpret_cast<const float4*>(base);
    float4 s1 = *reinterpret_cast<const float4*>(base + stride);
    float4 s2 = *reinterpret_cast<const float4*>(base + 2 * stride);
    float4 s3 = *reinterpret_cast<const float4*>(base + 3 * stride);
    float4 bv = *reinterpret_cast<const float4*>(bias + o4 * 4);
    float4 r;
    r.x = s0.x + s1.x + s2.x + s3.x + bv.x;
    r.y = s0.y + s1.y + s2.y + s3.y + bv.y;
    r.z = s0.z + s1.z + s2.z + s3.z + bv.z;
    r.w = s0.w + s1.w + s2.w + s3.w + bv.w;
    *reinterpret_cast<float4*>(out + b * 4096 + o4 * 4) = r;
}

// ---------------------------------------------------------------------------
extern "C" void kernel_launch(void* const* d_in, const int* in_sizes, int n_in,
                              void* d_out, int out_size, void* d_ws, size_t ws_size,
                              hipStream_t stream) {
    const float* x    = (const float*)d_in[0];
    const float* c1w  = (const float*)d_in[1];
    const float* c1b  = (const float*)d_in[2];
    const float* c2w  = (const float*)d_in[3];
    const float* c2b  = (const float*)d_in[4];
    const float* lc1w = (const float*)d_in[5];
    const float* lc1b = (const float*)d_in[6];
    const float* lc2w = (const float*)d_in[7];
    const float* lc2b = (const float*)d_in[8];
    const float* lc3w = (const float*)d_in[9];
    const float* lc3b = (const float*)d_in[10];
    const float* fcw  = (const float*)d_in[11];
    const float* fcb  = (const float*)d_in[12];
    float* out = (float*)d_out;

    float* ws  = (float*)d_ws;
    float* h1p = ws;                 // 32*32*71*71 = 5,161,472
    float* h2  = h1p + 5161472;      // 32*16*63*63 = 2,032,128
    float* h3  = h2  + 2032128;      // 32*16*55*55 = 1,548,800
    float* h4  = h3  + 1548800;      // 32*16*25*25 =   320,000
    float* h5  = h4  + 320000;       // 32*16*21*21 =   225,792
    float* fc_part = h1p;            // conv1 output dead by fc time

    conv1_pool_v2_kernel<<<dim3(25, 4, 32), 256, 0, stream>>>(x, c1w, c1b, h1p);
    conv2_kernel<<<dim3(16, 32), 256, 0, stream>>>(h1p, c2w, c2b, h2);
    lc_v9_kernel<9, 1, 63, 63, 55, 55><<<dim3(55 * 55), 512, 0, stream>>>(h2, lc1w, lc1b, h3);
    lc_v9_kernel<7, 2, 55, 55, 25, 25><<<dim3(25 * 25), 512, 0, stream>>>(h3, lc2w, lc2b, h4);
    lc_v9_kernel<5, 1, 25, 25, 21, 21><<<dim3(21 * 21), 512, 0, stream>>>(h4, lc3w, lc3b, h5);
    fc_v6_kernel<<<dim3(256, 4), 512, 0, stream>>>(h5, fcw, fc_part);
    fc_reduce_kernel<<<dim3(128), 256, 0, stream>>>(fc_part, fcb, out);
}

// Round 13
// 752.366 us; speedup vs baseline: 2.2097x; 1.1749x over previous
//
#include <hip/hip_runtime.h>

// Bijective XCD-aware block swizzle (m204 variant; safe for nwg % 8 != 0).
__device__ __forceinline__ int xcd_swizzle(int bid, int nwg) {
    int q = nwg >> 3, r = nwg & 7;
    int xcd = bid & 7, idx = bid >> 3;
    return (xcd < r) ? xcd * (q + 1) + idx
                     : r * (q + 1) + (xcd - r) * q + idx;
}

// ---------------------------------------------------------------------------
// Stage 1 v2: conv1 (11x11, Cin=1, Cout=32) + ReLU + maxpool 3x3 s2 ceil.
// ---------------------------------------------------------------------------
__global__ __launch_bounds__(256, 4) void conv1_pool_v2_kernel(
    const float* __restrict__ x, const float* __restrict__ w,
    const float* __restrict__ bias, float* __restrict__ out)
{
    const int tile = blockIdx.x;          // 0..24
    const int cog  = blockIdx.y;          // 0..3  (8 couts each)
    const int b    = blockIdx.z;          // 0..31
    const int ty = tile / 5, tx = tile % 5;
    const int pr0 = ty * 16, pc0 = tx * 16;   // pooled origin
    const int cr0 = pr0 * 2, cc0 = pc0 * 2;   // conv origin

    __shared__ float in_s[43 * 44];
    __shared__ float w_s[8][121];
    __shared__ float hp_s[33][8][17];

    const int tid = threadIdx.x;

    const float* xb = x + b * 152 * 152;
    for (int i = tid; i < 43 * 44; i += 256) {
        int r = i / 44, c = i - r * 44;
        int ir = cr0 + r, ic = cc0 + c;
        in_s[i] = (ir < 152 && ic < 152) ? xb[ir * 152 + ic] : 0.f;
    }
    for (int i = tid; i < 8 * 121; i += 256) {
        int co = i / 121, k = i - co * 121;
        w_s[co][k] = w[(cog * 8 + co) * 121 + k];
    }
    __syncthreads();

    for (int task = tid; task < 264; task += 256) {
        const int co  = task & 7;
        const int row = task >> 3;
        float hmax[16];
        if (cr0 + row < 142) {
            float acc[33];
            #pragma unroll
            for (int px = 0; px < 33; ++px) acc[px] = 0.f;
            #pragma unroll 1
            for (int kh = 0; kh < 11; ++kh) {
                float4 rq[11];
                #pragma unroll
                for (int j = 0; j < 11; ++j)
                    rq[j] = *reinterpret_cast<const float4*>(
                        &in_s[(row + kh) * 44 + j * 4]);
                const float* rr = reinterpret_cast<const float*>(rq);
                #pragma unroll
                for (int kw = 0; kw < 11; ++kw) {
                    float wv = w_s[co][kh * 11 + kw];
                    #pragma unroll
                    for (int px = 0; px < 33; ++px)
                        acc[px] += rr[px + kw] * wv;
                }
            }
            const float bv = bias[cog * 8 + co];
            #pragma unroll
            for (int px = 0; px < 33; ++px) {
                float v = fmaxf(acc[px] + bv, 0.f);
                acc[px] = (cc0 + px < 142) ? v : 0.f;
            }
            #pragma unroll
            for (int pc = 0; pc < 16; ++pc)
                hmax[pc] = fmaxf(fmaxf(acc[2 * pc], acc[2 * pc + 1]), acc[2 * pc + 2]);
        } else {
            #pragma unroll
            for (int pc = 0; pc < 16; ++pc) hmax[pc] = 0.f;
        }
        #pragma unroll
        for (int pc = 0; pc < 16; ++pc) hp_s[row][co][pc] = hmax[pc];
    }
    __syncthreads();

    for (int t = tid; t < 2048; t += 256) {
        int co = t >> 8, r = t & 255;
        int ppy = r >> 4, ppc = r & 15;
        float v = fmaxf(fmaxf(hp_s[2 * ppy][co][ppc], hp_s[2 * ppy + 1][co][ppc]),
                        hp_s[2 * ppy + 2][co][ppc]);
        int pr = pr0 + ppy, pc = pc0 + ppc;
        if (pr < 71 && pc < 71)
            out[((b * 32 + cog * 8 + co) * 71 + pr) * 71 + pc] = v;
    }
}

// ---------------------------------------------------------------------------
// Stage 2: conv2 (9x9, Cin=32, Cout=16) + ReLU   (unchanged)
// ---------------------------------------------------------------------------
__global__ __launch_bounds__(256) void conv2_kernel(
    const float* __restrict__ in, const float* __restrict__ w,
    const float* __restrict__ bias, float* __restrict__ out)
{
    const int tile = blockIdx.x;
    const int b = blockIdx.y;
    const int ty = tile / 4, tx = tile % 4;
    const int oh0 = ty * 16, ow0 = tx * 16;

    __shared__ float in_s[4][24][25];
    __shared__ float w_s[16][324];

    const int tid = threadIdx.x;
    const int co = tid / 16;
    const int py = tid % 16;

    float acc[16];
    #pragma unroll
    for (int i = 0; i < 16; ++i) acc[i] = 0.f;

    for (int cc = 0; cc < 8; ++cc) {
        for (int i = tid; i < 4 * 24 * 24; i += 256) {
            int ci = i / 576, r = (i / 24) % 24, c = i % 24;
            int ih = oh0 + r, iw = ow0 + c;
            float v = 0.f;
            if (ih < 71 && iw < 71)
                v = in[((b * 32 + cc * 4 + ci) * 71 + ih) * 71 + iw];
            in_s[ci][r][c] = v;
        }
        for (int i = tid; i < 16 * 324; i += 256) {
            int c2 = i / 324, t = i % 324;
            w_s[c2][t] = w[c2 * 2592 + cc * 324 + t];
        }
        __syncthreads();

        #pragma unroll 1
        for (int ci = 0; ci < 4; ++ci) {
            #pragma unroll 1
            for (int kh = 0; kh < 9; ++kh) {
                float rr[24];
                #pragma unroll
                for (int c = 0; c < 24; ++c) rr[c] = in_s[ci][py + kh][c];
                #pragma unroll
                for (int kw = 0; kw < 9; ++kw) {
                    float wv = w_s[co][ci * 81 + kh * 9 + kw];
                    #pragma unroll
                    for (int px = 0; px < 16; ++px)
                        acc[px] += rr[kw + px] * wv;
                }
            }
        }
        __syncthreads();
    }

    const int oh = oh0 + py;
    if (oh < 63) {
        const float bv = bias[co];
        #pragma unroll
        for (int px = 0; px < 16; ++px) {
            int ow = ow0 + px;
            if (ow < 63)
                out[((b * 16 + co) * 63 + oh) * 63 + ow] = fmaxf(acc[px] + bv, 0.f);
        }
    }
}

// ---------------------------------------------------------------------------
// Stages 3-5 v10: locally-connected conv + ReLU.
// = v9 minus the weight prefetch (wvn deleted; wv loaded at top of each
// pass). -16 VGPR (84 -> ~68) -> 7 waves/SIMD -> 3 independent blocks/CU
// instead of 2. The TLP bet: v9's one-pass prefetch bought only 8%; resident
// independent blocks at different barrier phases hide per-pass latency
// better. Everything else identical to v9 (LDS dbuf staging, int4 offset
// table, raw lgkmcnt-only barrier, XCD swizzle, no launch-bounds cap).
// ---------------------------------------------------------------------------
template<int KS, int STRIDE, int HIN, int WIN, int HOUT, int WOUT>
__global__ __launch_bounds__(512) void lc_v10_kernel(
    const float* __restrict__ in, const float* __restrict__ w,
    const float* __restrict__ bias, float* __restrict__ out)
{
    constexpr int K     = 16 * KS * KS;
    constexpr int K2    = KS * KS;
    constexpr int NPASS = (K + 127) / 128;
    constexpr int KPAD  = NPASS * 128;
    constexpr int HW    = HOUT * WOUT;
    constexpr int CHW   = 16 * HIN * WIN;

    __shared__ float patch_s[2][4096];     // 32 KB
    __shared__ int   base_s[KPAD];         // <= 5.6 KB

    const int tid = threadIdx.x;
    const int pos = xcd_swizzle(blockIdx.x, HW);
    const int oh = pos / WOUT, ow = pos % WOUT;
    const int posoff = (oh * STRIDE) * WIN + ow * STRIDE;

    // position-independent gather-offset table (built once)
    for (int k = tid; k < KPAD; k += 512) {
        int v = 0;
        if (k < K) {
            int ci = k / K2;
            int r  = k - ci * K2;
            int kh = r / KS, kw = r - kh * KS;
            v = ci * (HIN * WIN) + kh * WIN + kw;
        }
        base_s[k] = v;
    }

    const int kl  = tid & 31;
    const int cog = (tid >> 5) & 3;
    const int bg  = tid >> 7;              // 0..3
    const int b0  = bg * 8;

    // staging role: thread stages float4 #tid (batch sb) and #tid+512 (sb+16)
    const int sb = tid >> 5;               // 0..15
    const int k0 = (tid & 31) * 4;         // k offset within 128-window
    const float* gsrc0 = in + sb * CHW + posoff;
    const float* gsrc1 = gsrc0 + 16 * CHW;

    const float* wbase = w + (size_t)pos * 16 * K;

    float acc[8][4];
    #pragma unroll
    for (int i = 0; i < 8; ++i)
        #pragma unroll
        for (int j = 0; j < 4; ++j) acc[i][j] = 0.f;

    __syncthreads();                       // table ready (full sync, once)

    {   // prologue: pass-0 patch only (weights loaded inside the pass loop)
        int4 off4 = *reinterpret_cast<const int4*>(&base_s[k0]);
        float t0x = gsrc0[off4.x], t0y = gsrc0[off4.y],
              t0z = gsrc0[off4.z], t0w = gsrc0[off4.w];
        float t1x = gsrc1[off4.x], t1y = gsrc1[off4.y],
              t1z = gsrc1[off4.z], t1w = gsrc1[off4.w];
        *reinterpret_cast<float4*>(&patch_s[0][tid * 4]) =
            make_float4(t0x, t0y, t0z, t0w);
        *reinterpret_cast<float4*>(&patch_s[0][2048 + tid * 4]) =
            make_float4(t1x, t1y, t1z, t1w);
    }
    asm volatile("s_waitcnt lgkmcnt(0)" ::: "memory");
    __builtin_amdgcn_s_barrier();

    int cur = 0;
    #pragma unroll 1
    for (int ps = 0; ps < NPASS; ++ps) {
        const bool more = (ps + 1 < NPASS);
        // current-pass weights -> regs (issued first; consumed mid-pass)
        float4 wv[4];
        {
            const int kw4 = ps * 128 + kl * 4;
            #pragma unroll
            for (int cj = 0; cj < 4; ++cj)
                wv[cj] = (kw4 < K)
                    ? *reinterpret_cast<const float4*>(wbase + (size_t)(cog * 4 + cj) * K + kw4)
                    : make_float4(0.f, 0.f, 0.f, 0.f);
        }
        // next-pass gathers -> regs (consumed at end of pass)
        float t0x, t0y, t0z, t0w, t1x, t1y, t1z, t1w;
        if (more) {
            int4 off4 = *reinterpret_cast<const int4*>(&base_s[(ps + 1) * 128 + k0]);
            t0x = gsrc0[off4.x]; t0y = gsrc0[off4.y];
            t0z = gsrc0[off4.z]; t0w = gsrc0[off4.w];
            t1x = gsrc1[off4.x]; t1y = gsrc1[off4.y];
            t1z = gsrc1[off4.z]; t1w = gsrc1[off4.w];
        }
        // compute current pass: 8 x (ds_read_b128 + 16 FMA)
        #pragma unroll
        for (int bi = 0; bi < 8; ++bi) {
            float4 pv = *reinterpret_cast<const float4*>(
                &patch_s[cur][(b0 + bi) * 128 + kl * 4]);
            #pragma unroll
            for (int cj = 0; cj < 4; ++cj)
                acc[bi][cj] += pv.x * wv[cj].x + pv.y * wv[cj].y
                             + pv.z * wv[cj].z + pv.w * wv[cj].w;
        }
        if (more) {
            *reinterpret_cast<float4*>(&patch_s[cur ^ 1][tid * 4]) =
                make_float4(t0x, t0y, t0z, t0w);
            *reinterpret_cast<float4*>(&patch_s[cur ^ 1][2048 + tid * 4]) =
                make_float4(t1x, t1y, t1z, t1w);
        }
        // LDS-only barrier: ds ops retired (lgkmcnt); global loads may
        // stay outstanding (counted vmcnt at their uses).
        asm volatile("s_waitcnt lgkmcnt(0)" ::: "memory");
        __builtin_amdgcn_s_barrier();
        cur ^= 1;
    }

    // reduce over the 32 kl lanes (masks 1..16 stay within 32-lane halves)
    #pragma unroll
    for (int bi = 0; bi < 8; ++bi)
        #pragma unroll
        for (int cj = 0; cj < 4; ++cj) {
            float v = acc[bi][cj];
            v += __shfl_xor(v, 1);
            v += __shfl_xor(v, 2);
            v += __shfl_xor(v, 4);
            v += __shfl_xor(v, 8);
            v += __shfl_xor(v, 16);
            acc[bi][cj] = v;
        }

    if (kl == 0) {
        float bv[4];
        #pragma unroll
        for (int cj = 0; cj < 4; ++cj)
            bv[cj] = bias[(cog * 4 + cj) * HW + pos];
        #pragma unroll
        for (int bi = 0; bi < 8; ++bi)
            #pragma unroll
            for (int cj = 0; cj < 4; ++cj) {
                int b = b0 + bi, co = cog * 4 + cj;
                out[(b * 16 + co) * HW + pos] = fmaxf(acc[bi][cj] + bv[cj], 0.f);
            }
    }
}

// ---------------------------------------------------------------------------
// Stage 6 v5 (REVERT from v6): FC (32,7056)@(4096,7056)^T, LDS-pipelined
// (round-8 version that was part of the 785 us total; v6's per-thread
// direct loads regressed ~120 us). Grid (256 o-blocks of 16, 4 K-splits).
// ---------------------------------------------------------------------------
__global__ __launch_bounds__(512) void fc_v5_kernel(
    const float* __restrict__ in, const float* __restrict__ w,
    float* __restrict__ part)
{
    constexpr int K = 7056, KR = 1764;
    constexpr int NPASS = (KR + 127) / 128;   // 14

    __shared__ float patch_s[2][4096];

    const int tid  = threadIdx.x;
    const int oblk = blockIdx.x;              // 0..255
    const int ks   = blockIdx.y;              // 0..3
    const int kbeg = ks * KR, klim = kbeg + KR;

    const int kl  = tid & 31;
    const int cog = (tid >> 5) & 3;
    const int bg  = tid >> 7;
    const int b0  = bg * 8;

    const int sb = tid >> 5;
    const int k0 = (tid & 31) * 4;
    const float* row0 = in + sb * K;
    const float* row1 = row0 + 16 * K;

    const float* wbase = w + (size_t)(oblk * 16) * K;

    // all k offsets and klim are multiples of 4 -> f4 either fully in or out
    auto ld4 = [&](const float* row, int kg) -> float4 {
        return (kg < klim) ? *reinterpret_cast<const float4*>(row + kg)
                           : make_float4(0.f, 0.f, 0.f, 0.f);
    };

    float acc[8][4];
    #pragma unroll
    for (int i = 0; i < 8; ++i)
        #pragma unroll
        for (int j = 0; j < 4; ++j) acc[i][j] = 0.f;

    float4 wv[4], wvn[4];
    float4 t0, t1;

    {   // prologue (pass 0)
        const int kw4 = kbeg + kl * 4;
        #pragma unroll
        for (int cj = 0; cj < 4; ++cj)
            wv[cj] = (kw4 < klim)
                ? *reinterpret_cast<const float4*>(wbase + (size_t)(cog * 4 + cj) * K + kw4)
                : make_float4(0.f, 0.f, 0.f, 0.f);
        t0 = ld4(row0, kbeg + k0);
        t1 = ld4(row1, kbeg + k0);
        *reinterpret_cast<float4*>(&patch_s[0][tid * 4]) = t0;
        *reinterpret_cast<float4*>(&patch_s[0][2048 + tid * 4]) = t1;
    }
    __syncthreads();

    int cur = 0;
    #pragma unroll 1
    for (int ps = 0; ps < NPASS; ++ps) {
        const bool more = (ps + 1 < NPASS);
        if (more) {
            const int kbn = kbeg + (ps + 1) * 128;
            t0 = ld4(row0, kbn + k0);
            t1 = ld4(row1, kbn + k0);
            const int kw4n = kbn + kl * 4;
            #pragma unroll
            for (int cj = 0; cj < 4; ++cj)
                wvn[cj] = (kw4n < klim)
                    ? *reinterpret_cast<const float4*>(wbase + (size_t)(cog * 4 + cj) * K + kw4n)
                    : make_float4(0.f, 0.f, 0.f, 0.f);
        }
        #pragma unroll
        for (int bi = 0; bi < 8; ++bi) {
            float4 pv = *reinterpret_cast<const float4*>(
                &patch_s[cur][(b0 + bi) * 128 + kl * 4]);
            #pragma unroll
            for (int cj = 0; cj < 4; ++cj)
                acc[bi][cj] += pv.x * wv[cj].x + pv.y * wv[cj].y
                             + pv.z * wv[cj].z + pv.w * wv[cj].w;
        }
        if (more) {
            *reinterpret_cast<float4*>(&patch_s[cur ^ 1][tid * 4]) = t0;
            *reinterpret_cast<float4*>(&patch_s[cur ^ 1][2048 + tid * 4]) = t1;
            #pragma unroll
            for (int cj = 0; cj < 4; ++cj) wv[cj] = wvn[cj];
        }
        __syncthreads();
        cur ^= 1;
    }

    #pragma unroll
    for (int bi = 0; bi < 8; ++bi)
        #pragma unroll
        for (int cj = 0; cj < 4; ++cj) {
            float v = acc[bi][cj];
            v += __shfl_xor(v, 1);
            v += __shfl_xor(v, 2);
            v += __shfl_xor(v, 4);
            v += __shfl_xor(v, 8);
            v += __shfl_xor(v, 16);
            acc[bi][cj] = v;
        }

    if (kl == 0) {
        #pragma unroll
        for (int bi = 0; bi < 8; ++bi)
            #pragma unroll
            for (int cj = 0; cj < 4; ++cj)
                part[(size_t)(ks * 32 + b0 + bi) * 4096 + oblk * 16 + cog * 4 + cj] =
                    acc[bi][cj];
    }
}

__global__ __launch_bounds__(256) void fc_reduce_kernel(
    const float* __restrict__ part, const float* __restrict__ bias,
    float* __restrict__ out)
{
    int i4 = blockIdx.x * 256 + threadIdx.x;
    if (i4 >= 32768) return;
    int b = i4 >> 10, o4 = i4 & 1023;
    const size_t stride = (size_t)32 * 4096;
    const float* base = part + (size_t)b * 4096 + o4 * 4;
    float4 s0 = *reinterpret_cast<const float4*>(base);
    float4 s1 = *reinterpret_cast<const float4*>(base + stride);
    float4 s2 = *reinterpret_cast<const float4*>(base + 2 * stride);
    float4 s3 = *reinterpret_cast<const float4*>(base + 3 * stride);
    float4 bv = *reinterpret_cast<const float4*>(bias + o4 * 4);
    float4 r;
    r.x = s0.x + s1.x + s2.x + s3.x + bv.x;
    r.y = s0.y + s1.y + s2.y + s3.y + bv.y;
    r.z = s0.z + s1.z + s2.z + s3.z + bv.z;
    r.w = s0.w + s1.w + s2.w + s3.w + bv.w;
    *reinterpret_cast<float4*>(out + b * 4096 + o4 * 4) = r;
}

// ---------------------------------------------------------------------------
extern "C" void kernel_launch(void* const* d_in, const int* in_sizes, int n_in,
                              void* d_out, int out_size, void* d_ws, size_t ws_size,
                              hipStream_t stream) {
    const float* x    = (const float*)d_in[0];
    const float* c1w  = (const float*)d_in[1];
    const float* c1b  = (const float*)d_in[2];
    const float* c2w  = (const float*)d_in[3];
    const float* c2b  = (const float*)d_in[4];
    const float* lc1w = (const float*)d_in[5];
    const float* lc1b = (const float*)d_in[6];
    const float* lc2w = (const float*)d_in[7];
    const float* lc2b = (const float*)d_in[8];
    const float* lc3w = (const float*)d_in[9];
    const float* lc3b = (const float*)d_in[10];
    const float* fcw  = (const float*)d_in[11];
    const float* fcb  = (const float*)d_in[12];
    float* out = (float*)d_out;

    float* ws  = (float*)d_ws;
    float* h1p = ws;                 // 32*32*71*71 = 5,161,472
    float* h2  = h1p + 5161472;      // 32*16*63*63 = 2,032,128
    float* h3  = h2  + 2032128;      // 32*16*55*55 = 1,548,800
    float* h4  = h3  + 1548800;      // 32*16*25*25 =   320,000
    float* h5  = h4  + 320000;       // 32*16*21*21 =   225,792
    float* fc_part = h1p;            // conv1 output dead by fc time

    conv1_pool_v2_kernel<<<dim3(25, 4, 32), 256, 0, stream>>>(x, c1w, c1b, h1p);
    conv2_kernel<<<dim3(16, 32), 256, 0, stream>>>(h1p, c2w, c2b, h2);
    lc_v10_kernel<9, 1, 63, 63, 55, 55><<<dim3(55 * 55), 512, 0, stream>>>(h2, lc1w, lc1b, h3);
    lc_v10_kernel<7, 2, 55, 55, 25, 25><<<dim3(25 * 25), 512, 0, stream>>>(h3, lc2w, lc2b, h4);
    lc_v10_kernel<5, 1, 25, 25, 21, 21><<<dim3(21 * 21), 512, 0, stream>>>(h4, lc3w, lc3b, h5);
    fc_v5_kernel<<<dim3(256, 4), 512, 0, stream>>>(h5, fcw, fc_part);
    fc_reduce_kernel<<<dim3(128), 256, 0, stream>>>(fc_part, fcb, out);
}